// Round 12
// baseline (100.933 us; speedup 1.0000x reference)
//
#include <hip/hip_runtime.h>
#include <hip/hip_bf16.h>

// y = x @ W^T + b ; x:(16,8192,256) f32, W:(256,256) f32, b:(256,) f32, out f32
// M=131072, N=256, K=256. Memory-bound.
// R12 = R8 (best-equal 58.8us) + PREFETCH DISTANCE 2 (two register sets):
//   at end of iter t: stage tile t+1 from its set, reload that set with t+3.
//   Loads stay in flight for TWO generations; issue points interleave ->
//   reads outstanding ~continuously (~128KB/CU). Little's law: tput=outst/lat;
//   R8's one-burst-per-gen left HBM idle most of each 7.35us generation
//   (fill kernel: 7.2 TB/s at 9.9% occupancy = continuous stream wins).
// History: R2 more blocks hurt; R3 transposed loads = VMEM death; R4/R10
//   stage-early -> wave drift -> partial-line write amp -> stage-at-end +
//   per-tile barrier is PROTECTIVE; R5 nt stores +3us (keep); R7 lane-owns-row
//   stores = write amp; R8 lgkm-only barrier null (drains free); R9 sc0sc1
//   write amp; R11 nt loads lose L3 hits (-7.5us) -> plain x loads.

typedef __attribute__((ext_vector_type(8))) short bf16x8;
typedef __attribute__((ext_vector_type(16))) float f32x16;

__device__ __forceinline__ short f2bf(float f) {
    __hip_bfloat16 h = __float2bfloat16(f);   // RTNE
    return *reinterpret_cast<short*>(&h);
}

#define BM   32
#define LDSK 264   // 256 + 8 pad: 528B row stride -> conflict-free b128 frag reads

__global__ __launch_bounds__(512, 4)
void rac_linear_kernel(const float* __restrict__ x,
                       const float* __restrict__ w,
                       const float* __restrict__ bias,
                       float* __restrict__ out,
                       int tiles_per_block)
{
    __shared__ short lds[2][BM * LDSK];   // 2 x 16.5 KB

    const int tid  = threadIdx.x;
    const int lane = tid & 63;
    const int wv   = tid >> 6;        // 0..7: N-wave, owns cols [wv*32, wv*32+32)
    const int l31  = lane & 31;
    const int lh   = lane >> 5;       // 0/1: k-half of the fragment
    const int srow = tid >> 6;        // staging row base
    const int skk  = (tid & 63) * 4;  // staging k offset

    // ---- B prologue: W[n][k] -> per-wave bf16 register fragments ----
    // B frag layout (32x32x16): col = lane&31 (n), k = (lane>>5)*8 + j
    bf16x8 bfrag[16];
    {
        const int   wrow = wv * 32 + l31;                 // n index
        const float* wb  = w + (size_t)wrow * 256 + lh * 8;
        #pragma unroll
        for (int ks = 0; ks < 16; ++ks) {
            const float4 lo = *reinterpret_cast<const float4*>(wb + ks * 16);
            const float4 hi = *reinterpret_cast<const float4*>(wb + ks * 16 + 4);
            bf16x8 b;
            b[0]=f2bf(lo.x); b[1]=f2bf(lo.y); b[2]=f2bf(lo.z); b[3]=f2bf(lo.w);
            b[4]=f2bf(hi.x); b[5]=f2bf(hi.y); b[6]=f2bf(hi.z); b[7]=f2bf(hi.w);
            bfrag[ks] = b;
        }
    }
    const float bval = bias[wv * 32 + l31];

    const int t0 = blockIdx.x * tiles_per_block;

    float4 vA[4], vB[4];   // two staging register sets (even / odd tiles)

    auto loadT = [&](float4* v, int g) {
        const float4* src = reinterpret_cast<const float4*>(x + (size_t)g * (BM * 256));
        #pragma unroll
        for (int i = 0; i < 4; ++i) v[i] = src[i * 512 + tid];   // fully coalesced
    };
    auto stageT = [&](const float4* v, int b) {
        #pragma unroll
        for (int i = 0; i < 4; ++i) {
            short4 s;
            s.x=f2bf(v[i].x); s.y=f2bf(v[i].y); s.z=f2bf(v[i].z); s.w=f2bf(v[i].w);
            *reinterpret_cast<short4*>(&lds[b][(i * 8 + srow) * LDSK + skk]) = s;
        }
    };
    auto compT = [&](int b, int g) {
        f32x16 acc;
        #pragma unroll
        for (int r = 0; r < 16; ++r) acc[r] = bval;
        const short* abase = &lds[b][l31 * LDSK + lh * 8];
        #pragma unroll
        for (int ks = 0; ks < 16; ++ks) {
            bf16x8 a = *reinterpret_cast<const bf16x8*>(abase + ks * 16);
            acc = __builtin_amdgcn_mfma_f32_32x32x16_bf16(a, bfrag[ks], acc, 0, 0, 0);
        }
        // C layout: col=lane&31, row=(r&3)+8*(r>>2)+4*(lane>>5).
        // 32 lanes sweep one row -> full 128B lines per instr (R7). nt: no reuse.
        float* ob = out + (size_t)g * (BM * 256) + wv * 32 + l31;
        const int rhi = lh * 4;
        #pragma unroll
        for (int r = 0; r < 16; ++r) {
            const int row = (r & 3) + 8 * (r >> 2) + rhi;
            __builtin_nontemporal_store(acc[r], &ob[(size_t)row * 256]);
        }
    };

    // ---- prologue: vA<-t0, vB<-t0+1; stage t0; vA reloads t0+2 ----
    loadT(vA, t0);
    loadT(vB, t0 + 1);
    stageT(vA, 0);          // waits vA only
    loadT(vA, t0 + 2);
    __syncthreads();        // one full drain at startup

    for (int t = 0; t < tiles_per_block; t += 2) {
        // ---- iter t (even): compute buf0 ----
        compT(0, t0 + t);
        if (t + 1 < tiles_per_block) stageT(vB, 1);        // tile t+1 (2-gen-old loads)
        if (t + 3 < tiles_per_block) loadT(vB, t0 + t + 3); // reload set B
        asm volatile("s_waitcnt lgkmcnt(0)\n\ts_barrier" ::: "memory");

        // ---- iter t+1 (odd): compute buf1 ----
        if (t + 1 < tiles_per_block) {
            compT(1, t0 + t + 1);
            if (t + 2 < tiles_per_block) stageT(vA, 0);        // tile t+2
            if (t + 4 < tiles_per_block) loadT(vA, t0 + t + 4); // reload set A
            if (t + 2 < tiles_per_block)
                asm volatile("s_waitcnt lgkmcnt(0)\n\ts_barrier" ::: "memory");
        }
    }
}

extern "C" void kernel_launch(void* const* d_in, const int* in_sizes, int n_in,
                              void* d_out, int out_size, void* d_ws, size_t ws_size,
                              hipStream_t stream)
{
    const float* x    = (const float*)d_in[0];
    const float* w    = (const float*)d_in[1];
    const float* bias = (const float*)d_in[2];
    float* out        = (float*)d_out;

    const int M      = in_sizes[0] / 256;   // 131072 rows
    const int ntiles = M / BM;              // 4096
    const int grid   = 512;                 // 2 blocks/CU
    const int tpb    = ntiles / grid;       // 8 tiles per block

    rac_linear_kernel<<<grid, 512, 0, stream>>>(x, w, bias, out, tpb);
}

// Round 13
// 65.936 us; speedup vs baseline: 1.5308x; 1.5308x over previous
//
#include <hip/hip_runtime.h>
#include <hip/hip_bf16.h>

// y = x @ W^T + b ; x:(16,8192,256) f32, W:(256,256) f32, b:(256,) f32, out f32
// M=131072, N=256, K=256. Memory-bound.
// R13 = R8 (best 58.8us) + LDS-TRANSPOSE EPILOGUE:
//   acc -> 32x256 f32 LDS tile (frag-layout writes, 2-way=free), barrier,
//   each wave reads 4 full out ROWS and nt-stores f32x4/lane = 1024B/instr.
//   Store instrs 16->4/thread; every instruction covers whole lines by itself
//   -> immune to wave skew (R7/R10/R12 all died to partial-line write amp).
// History: R2 more blocks hurt; R3 transposed loads = VMEM death; R4/R10/R12
//   schedule shifts -> skewed nt halves -> FETCH/WRITE amp -> lockstep is
//   protective; R5 nt stores +3us (keep); R8 lgkm-only barrier null;
//   R9 sc0sc1 amp; R11 nt loads lose L3 hits.

typedef __attribute__((ext_vector_type(8))) short bf16x8;
typedef __attribute__((ext_vector_type(16))) float f32x16;
typedef __attribute__((ext_vector_type(4)))  float f32x4;

__device__ __forceinline__ short f2bf(float f) {
    __hip_bfloat16 h = __float2bfloat16(f);   // RTNE
    return *reinterpret_cast<short*>(&h);
}

#define BM   32
#define LDSK 264   // 256 + 8 pad: 528B row stride -> conflict-free b128 frag reads

__global__ __launch_bounds__(512, 4)
void rac_linear_kernel(const float* __restrict__ x,
                       const float* __restrict__ w,
                       const float* __restrict__ bias,
                       float* __restrict__ out,
                       int tiles_per_block)
{
    __shared__ short lds[2][BM * LDSK];   // 2 x 16.5 KB staging
    __shared__ float ebuf[BM * 256];      // 32 KB epilogue transpose tile

    const int tid  = threadIdx.x;
    const int lane = tid & 63;
    const int wv   = tid >> 6;        // 0..7: N-wave, owns cols [wv*32, wv*32+32)
    const int l31  = lane & 31;
    const int lh   = lane >> 5;       // 0/1: k-half of the fragment

    // ---- B prologue: W[n][k] -> per-wave bf16 register fragments ----
    // B frag layout (32x32x16): col = lane&31 (n), k = (lane>>5)*8 + j
    bf16x8 bfrag[16];
    {
        const int   wrow = wv * 32 + l31;                 // n index
        const float* wb  = w + (size_t)wrow * 256 + lh * 8;
        #pragma unroll
        for (int ks = 0; ks < 16; ++ks) {
            const float4 lo = *reinterpret_cast<const float4*>(wb + ks * 16);
            const float4 hi = *reinterpret_cast<const float4*>(wb + ks * 16 + 4);
            bf16x8 b;
            b[0]=f2bf(lo.x); b[1]=f2bf(lo.y); b[2]=f2bf(lo.z); b[3]=f2bf(lo.w);
            b[4]=f2bf(hi.x); b[5]=f2bf(hi.y); b[6]=f2bf(hi.z); b[7]=f2bf(hi.w);
            bfrag[ks] = b;
        }
    }
    const float bval = bias[wv * 32 + l31];

    const int t0 = blockIdx.x * tiles_per_block;

    float4 v[4];   // staging registers (one BM x 256 f32 tile = 64 B/thread)

    // prologue: load + stage tile t0 into buf 0
    {
        const float4* src = reinterpret_cast<const float4*>(x + (size_t)t0 * (BM * 256));
        #pragma unroll
        for (int i = 0; i < 4; ++i) v[i] = src[i * 512 + tid];   // fully coalesced
        #pragma unroll
        for (int i = 0; i < 4; ++i) {
            const int row = i * 8 + (tid >> 6);      // elem = i*2048 + tid*4
            const int k   = (tid & 63) * 4;
            short4 s;
            s.x=f2bf(v[i].x); s.y=f2bf(v[i].y); s.z=f2bf(v[i].z); s.w=f2bf(v[i].w);
            *reinterpret_cast<short4*>(&lds[0][row * LDSK + k]) = s;
        }
    }

    for (int t = 0; t < tiles_per_block; ++t) {
        const int buf  = t & 1;
        const int tile = t0 + t;

        // gen-top barrier: staging visible; prev-gen ebuf reads done.
        asm volatile("s_waitcnt lgkmcnt(0)\n\ts_barrier" ::: "memory");

        // issue next tile's global loads early (latency hidden under compute)
        if (t + 1 < tiles_per_block) {
            const float4* src =
                reinterpret_cast<const float4*>(x + (size_t)(tile + 1) * (BM * 256));
            #pragma unroll
            for (int i = 0; i < 4; ++i) v[i] = src[i * 512 + tid];
        }

        // ---- compute: 16 K-steps of mfma_f32_32x32x16_bf16 ----
        f32x16 acc;
        #pragma unroll
        for (int r = 0; r < 16; ++r) acc[r] = bval;

        // A frag layout: row = lane&31 (m), k = (lane>>5)*8 + j
        const short* abase = &lds[buf][l31 * LDSK + lh * 8];
        #pragma unroll
        for (int ks = 0; ks < 16; ++ks) {
            bf16x8 a = *reinterpret_cast<const bf16x8*>(abase + ks * 16);
            acc = __builtin_amdgcn_mfma_f32_32x32x16_bf16(a, bfrag[ks], acc, 0, 0, 0);
        }

        // ---- epilogue 1: acc -> ebuf (frag layout: row=(r&3)+8*(r>>2)+4*lh,
        //      col=wv*32+l31). Lanes of one r hit 2 rows x contiguous 128B:
        //      2-way bank aliasing = free (m136). ----
        {
            const int ecol = wv * 32 + l31;
            #pragma unroll
            for (int r = 0; r < 16; ++r) {
                const int row = (r & 3) + 8 * (r >> 2) + lh * 4;
                ebuf[row * 256 + ecol] = acc[r];
            }
        }
        asm volatile("s_waitcnt lgkmcnt(0)\n\ts_barrier" ::: "memory");

        // ---- epilogue 2: wave reads rows {wv, 8+wv, 16+wv, 24+wv} and
        //      nt-stores 1024B per instruction (skew-immune full lines). ----
        {
            float* ob = out + (size_t)tile * (BM * 256);
            #pragma unroll
            for (int i = 0; i < 4; ++i) {
                const int row = i * 8 + wv;
                const f32x4 val =
                    *reinterpret_cast<const f32x4*>(&ebuf[row * 256 + lane * 4]);
                __builtin_nontemporal_store(
                    val, reinterpret_cast<f32x4*>(ob + (size_t)row * 256 + lane * 4));
            }
        }

        // stage next tile into the other buffer (all waves past barrier2)
        if (t + 1 < tiles_per_block) {
            #pragma unroll
            for (int i = 0; i < 4; ++i) {
                const int row = i * 8 + (tid >> 6);
                const int k   = (tid & 63) * 4;
                short4 s;
                s.x=f2bf(v[i].x); s.y=f2bf(v[i].y); s.z=f2bf(v[i].z); s.w=f2bf(v[i].w);
                *reinterpret_cast<short4*>(&lds[buf ^ 1][row * LDSK + k]) = s;
            }
        }
    }
}

extern "C" void kernel_launch(void* const* d_in, const int* in_sizes, int n_in,
                              void* d_out, int out_size, void* d_ws, size_t ws_size,
                              hipStream_t stream)
{
    const float* x    = (const float*)d_in[0];
    const float* w    = (const float*)d_in[1];
    const float* bias = (const float*)d_in[2];
    float* out        = (float*)d_out;

    const int M      = in_sizes[0] / 256;   // 131072 rows
    const int ntiles = M / BM;              // 4096
    const int grid   = 512;                 // 2 blocks/CU
    const int tpb    = ntiles / grid;       // 8 tiles per block

    rac_linear_kernel<<<grid, 512, 0, stream>>>(x, w, bias, out, tpb);
}